// Round 6
// baseline (983.618 us; speedup 1.0000x reference)
//
#include <hip/hip_runtime.h>
#include <cstdint>

// ---------------- geometry ----------------
// B=8, L=1024, D_MODEL=1024, H=16, DK=DV=64.  S = 8192 tokens.
// outputs: d_out[0 .. 8388608) = LN output fp32, then attn [8,16,1024,1024] fp32.

// ---------------- workspace layout (bytes) ----------------
#define WS_XB   0u                       // Xbf bf16 [8192][1024]            16,777,216
#define WS_WT   16777216u                // Wqkv^T bf16 [3072][1024]          6,291,456
#define WS_WOT  (WS_WT + 6291456u)       // W_O^T bf16 [1024][1024]           2,097,152
#define WS_M8   (WS_WOT + 2097152u)      // mask BITS [8][1024][32 u32]       1,048,576
#define WS_Q    (WS_M8 + 8388608u)       // Q bf16 [128][1024][64] (pre-scaled by 1/8)
#define WS_K    (WS_Q + 16777216u)       // K bf16 [128][1024][64]
#define WS_V    (WS_K + 16777216u)       // V^T bf16 [128][64][1024]
// ctx bf16 aliases WS_XB (X-bf16 dead after QKV GEMM)
// Y fp32 [8192][1024] aliases WS_Q..WS_K+ (Q/K dead after attention)

typedef short v8s __attribute__((ext_vector_type(8)));
typedef float v4f __attribute__((ext_vector_type(4)));

__device__ __forceinline__ short bf16rn(float f) {
  uint32_t u = __builtin_bit_cast(uint32_t, f);
  u += 0x7fffu + ((u >> 16) & 1u);
  return (short)(u >> 16);
}
__device__ __forceinline__ uint32_t bfpack(float a, float b) {
  return (uint32_t)(uint16_t)bf16rn(a) | ((uint32_t)(uint16_t)bf16rn(b) << 16);
}
__device__ __forceinline__ float bf2f(uint16_t h) {
  uint32_t u = ((uint32_t)h) << 16;
  return __builtin_bit_cast(float, u);
}
__device__ __forceinline__ v4f mfma16(v8s a, v8s b, v4f c) {
  return __builtin_amdgcn_mfma_f32_16x16x32_bf16(a, b, c, 0, 0, 0);
}
// async global->LDS, 16B per lane.  LDS dest is wave-uniform base + lane*16.
__device__ __forceinline__ void gload16(const short* g, short* l) {
  __builtin_amdgcn_global_load_lds(
      (const __attribute__((address_space(1))) unsigned int*)g,
      (__attribute__((address_space(3))) unsigned int*)l, 16, 0, 0);
}

// ---------------- fused prep: X->bf16 and mask->bits ----------------
// blocks [0,8192): cvt (float4/lane).  blocks [8192,40960): mask bits via ballot.
__global__ void k_prep(const float* __restrict__ X, short* __restrict__ Xb,
                       const int* __restrict__ M, uint32_t* __restrict__ Mb) {
  int bid = blockIdx.x;
  if (bid < 8192) {
    int i = (bid * 256 + threadIdx.x) * 4;
    float4 v = *(const float4*)(X + i);
    short4 o;
    o.x = bf16rn(v.x); o.y = bf16rn(v.y); o.z = bf16rn(v.z); o.w = bf16rn(v.w);
    *(short4*)(Xb + i) = o;
  } else {
    int i = (bid - 8192) * 256 + threadIdx.x;
    unsigned long long bal = __ballot(M[i] != 0);
    int lane = threadIdx.x & 63;
    if (lane == 0)       Mb[i >> 5] = (uint32_t)bal;
    else if (lane == 32) Mb[i >> 5] = (uint32_t)(bal >> 32);
  }
}

// transpose+convert all four weight matrices.  grid (32, 128), block (32,8).
__global__ void k_tw(const float* __restrict__ WQ, const float* __restrict__ WK,
                     const float* __restrict__ WV, const float* __restrict__ WO,
                     short* __restrict__ Wt, short* __restrict__ WOt) {
  __shared__ float tile[32][33];
  int k0 = blockIdx.x * 32, n0 = blockIdx.y * 32;
  int tx = threadIdx.x, ty = threadIdx.y;
  const float* src; short* dst; int nloc, drow;
  if (n0 < 3072) {
    int wsel = n0 >> 10;
    src = wsel == 0 ? WQ : (wsel == 1 ? WK : WV);
    nloc = n0 & 1023; dst = Wt; drow = n0;
  } else {
    src = WO; nloc = n0 - 3072; dst = WOt; drow = n0 - 3072;
  }
#pragma unroll
  for (int i = 0; i < 4; ++i)
    tile[ty + 8 * i][tx] = src[(size_t)(k0 + ty + 8 * i) * 1024 + nloc + tx];
  __syncthreads();
#pragma unroll
  for (int i = 0; i < 4; ++i)
    dst[(size_t)(drow + ty + 8 * i) * 1024 + k0 + tx] = bf16rn(tile[tx][ty + 8 * i]);
}

// ---------------- 128x128 MFMA GEMM (m97-style: global_load_lds, linear LDS) ----------------
// MODE 0: C = Xbf @ Wqkv  -> scatter bf16 into Q (pre-scaled 1/8) / K [bh][l][64];
//                            V transposed [bh][64][l]
// MODE 1: C = ctx @ W_O   -> Y = C + Xres (fp32)
template <int MODE>
__global__ __launch_bounds__(256) void k_gemm(const short* __restrict__ A,
                                              const short* __restrict__ Bt,
                                              short* __restrict__ Q, short* __restrict__ Kp,
                                              short* __restrict__ V,
                                              const float* __restrict__ Xres,
                                              float* __restrict__ Y) {
  __shared__ short As[128 * 32];   // linear: rows of 32 shorts (64B) — required by gload_lds
  __shared__ short Bs[128 * 32];
  // XCD-aware bijective swizzle (grid % 8 == 0): each XCD gets contiguous m-panels.
  const int nwg = gridDim.x * gridDim.y;
  const int id = blockIdx.y * gridDim.x + blockIdx.x;
  const int swz = (id & 7) * (nwg >> 3) + (id >> 3);
  const int bx = swz % gridDim.x, by = swz / gridDim.x;
  const int m0 = by * 128, n0 = bx * 128;
  const int t = threadIdx.x, w = t >> 6, lane = t & 63, col = lane & 15, quad = lane >> 4;
  const int wm = w >> 1, wn = w & 1;
  const v4f vz = {0.f, 0.f, 0.f, 0.f};
  v4f acc[4][4];
#pragma unroll
  for (int i = 0; i < 4; ++i)
#pragma unroll
    for (int j = 0; j < 4; ++j) acc[i][j] = vz;

  // staging: wave w stages rows [w*32, w*32+32), 2 instrs of 1024B each.
  const int srow = lane >> 2, sseg = lane & 3;
  const short* ga = A + (size_t)(m0 + w * 32 + srow) * 1024 + sseg * 8;
  const short* gb = Bt + (size_t)(n0 + w * 32 + srow) * 1024 + sseg * 8;
  short* la = As + (w * 32) * 32;   // wave-uniform LDS base
  short* lb = Bs + (w * 32) * 32;

  for (int kc = 0; kc < 32; ++kc) {
    __syncthreads();                       // fragments of kc-1 consumed
    gload16(ga + kc * 32, la);
    gload16(ga + kc * 32 + 16 * 1024, la + 16 * 32);
    gload16(gb + kc * 32, lb);
    gload16(gb + kc * 32 + 16 * 1024, lb + 16 * 32);
    __syncthreads();                       // compiler drains vmcnt before barrier
    v8s af[4], bf[4];
#pragma unroll
    for (int i = 0; i < 4; ++i) {
      af[i] = *(const v8s*)(As + (wm * 64 + i * 16 + col) * 32 + quad * 8);
      bf[i] = *(const v8s*)(Bs + (wn * 64 + i * 16 + col) * 32 + quad * 8);
    }
#pragma unroll
    for (int mi = 0; mi < 4; ++mi)
#pragma unroll
      for (int ni = 0; ni < 4; ++ni)
        acc[mi][ni] = mfma16(af[mi], bf[ni], acc[mi][ni]);
  }

  if (MODE == 0) {
    const int which = n0 >> 10;            // uniform per block
    if (which == 2) {
      // V^T scatter: 4 rg values are 4 consecutive l at fixed d -> packed short4
#pragma unroll
      for (int mi = 0; mi < 4; ++mi)
#pragma unroll
        for (int ni = 0; ni < 4; ++ni) {
          int n = n0 + wn * 64 + ni * 16 + col;
          int h = (n >> 6) & 15, d = n & 63;
          int mbase = m0 + wm * 64 + mi * 16 + quad * 4;
          int b = mbase >> 10, l = mbase & 1023;
          short4 pk;
          pk.x = bf16rn(acc[mi][ni][0]); pk.y = bf16rn(acc[mi][ni][1]);
          pk.z = bf16rn(acc[mi][ni][2]); pk.w = bf16rn(acc[mi][ni][3]);
          *(short4*)(V + ((size_t)((b * 16 + h) * 64 + d)) * 1024 + l) = pk;
        }
    } else {
      short* dst = which == 0 ? Q : Kp;
      // fold 1/sqrt(dk)=0.125 into Q (exact exponent shift in bf16)
      const float qs = which == 0 ? 0.125f : 1.0f;
#pragma unroll
      for (int mi = 0; mi < 4; ++mi)
#pragma unroll
        for (int ni = 0; ni < 4; ++ni) {
          int n = n0 + wn * 64 + ni * 16 + col;
          int h = (n >> 6) & 15, d = n & 63;
          int mbase = m0 + wm * 64 + mi * 16 + quad * 4;
#pragma unroll
          for (int rg = 0; rg < 4; ++rg) {
            int m = mbase + rg, b = m >> 10, l = m & 1023;
            dst[((size_t)((b * 16 + h) * 1024 + l)) * 64 + d] = bf16rn(acc[mi][ni][rg] * qs);
          }
        }
    }
  } else {
#pragma unroll
    for (int mi = 0; mi < 4; ++mi)
#pragma unroll
      for (int ni = 0; ni < 4; ++ni) {
        int n = n0 + wn * 64 + ni * 16 + col;
        int mbase = m0 + wm * 64 + mi * 16 + quad * 4;
#pragma unroll
        for (int rg = 0; rg < 4; ++rg) {
          int m = mbase + rg;
          Y[(size_t)m * 1024 + n] = acc[mi][ni][rg] + Xres[(size_t)m * 1024 + n];
        }
      }
  }
}

// ---------------- fused attention (single QK pass, staged K, P in registers) ----------------
// grid (32 q-tiles, 128 bh) -> XCD-swizzled, block 256.
// Pass A: K tiles staged via LDS (padded 72, reg-staged) with T14 async-split:
//   issue tile s+1's global loads BEFORE computing tile s, write them to LDS
//   after the read-barrier -> HBM/L2 latency hides under MFMA+exp (R3 lesson:
//   direct-global MFMA operands cost ~100us).  exp computed ONCE, kept as 64
//   packed-bf16 u32/lane (static indexing).  Masks preloaded (16 regs).
// Pass B: unpack -> *1/L -> attn write direct from regs; repack -> Pb -> PV
//   (V^T direct from global, L2-hot).  Softmax without max-subtraction.
__global__ __launch_bounds__(256) void k_attn(const short* __restrict__ Qb,
                                              const short* __restrict__ Kb,
                                              const short* __restrict__ Vt,
                                              const uint32_t* __restrict__ Mb,
                                              float* __restrict__ attn,
                                              short* __restrict__ ctxb) {
  __shared__ short Ks[128 * 72];    // K tile, rows padded to 72 shorts (18.4 KB)
  __shared__ short Pb[32 * 136];    // P tile bf16, rows padded to 136 shorts
  __shared__ float red[4][32];
  __shared__ float fin[32];

  // XCD swizzle: 4096 blocks, each XCD gets 512 contiguous (bh, q-tile) ids.
  const int lid = blockIdx.y * 32 + blockIdx.x;
  const int swz = (lid & 7) * 512 + (lid >> 3);
  const int bh = swz >> 5, q0 = (swz & 31) * 32, b = bh >> 4, h = bh & 15;
  const int t = threadIdx.x, w = t >> 6, lane = t & 63, col = lane & 15, quad = lane >> 4;
  const v4f vz = {0.f, 0.f, 0.f, 0.f};

  // Q fragments (MFMA B-operand): [q-tile][d-half], held all kernel (Q pre-scaled 1/8)
  v8s qf[2][2];
#pragma unroll
  for (int qt = 0; qt < 2; ++qt)
#pragma unroll
    for (int dh2 = 0; dh2 < 2; ++dh2)
      qf[qt][dh2] = *(const v8s*)(Qb + ((size_t)bh * 1024 + q0 + qt * 16 + col) * 64 + dh2 * 32 + quad * 8);

  const size_t kvbase = (size_t)bh * 1024;
  // mask bits: u32 index = (b*1024+q)*32 + s*4 + w ; bit = kt*16 + quad*4 + rg
  const uint32_t* mrow0 = Mb + ((size_t)(b * 1024 + q0 + col)) * 32 + w;
  const uint32_t* mrow1 = mrow0 + 16 * 32;
  uint32_t mk[2][8];
#pragma unroll
  for (int s = 0; s < 8; ++s) { mk[0][s] = mrow0[s * 4]; mk[1][s] = mrow1[s * 4]; }

  // K staging: 2 lanes/row, 64B each (reg-staged into padded LDS)
  const int r = t >> 1, sg = t & 1;
  const short* gk0 = Kb + (kvbase + r) * 64 + sg * 32;
  short* lk = Ks + r * 72 + sg * 32;

  uint32_t pun[8][2][2][2];   // [s][kt][qt][pair] packed bf16 exp(S), unnormalized
  float lr[2] = {0.f, 0.f};

  // prologue: stage tile 0
  {
    int4 c0 = ((const int4*)gk0)[0], c1 = ((const int4*)gk0)[1];
    int4 c2 = ((const int4*)gk0)[2], c3 = ((const int4*)gk0)[3];
    ((int4*)lk)[0] = c0; ((int4*)lk)[1] = c1; ((int4*)lk)[2] = c2; ((int4*)lk)[3] = c3;
  }
  __syncthreads();

  // ---- pass A: QK^T + exp, once, K from LDS, next tile prefetched early ----
#pragma unroll
  for (int s = 0; s < 8; ++s) {
    int4 n0, n1, n2, n3;
    if (s < 7) {                       // issue next-tile loads BEFORE compute
      const short* gk = gk0 + (size_t)(s + 1) * 128 * 64;
      n0 = ((const int4*)gk)[0]; n1 = ((const int4*)gk)[1];
      n2 = ((const int4*)gk)[2]; n3 = ((const int4*)gk)[3];
    }
    __builtin_amdgcn_s_setprio(1);
#pragma unroll
    for (int kt = 0; kt < 2; ++kt) {
      int kr0 = w * 32 + kt * 16;
      v8s a0 = *(const v8s*)(Ks + (kr0 + col) * 72 + quad * 8);
      v8s a1 = *(const v8s*)(Ks + (kr0 + col) * 72 + 32 + quad * 8);
#pragma unroll
      for (int qt = 0; qt < 2; ++qt) {
        uint32_t mu = mk[qt][s];
        v4f c = mfma16(a0, qf[qt][0], vz);
        c = mfma16(a1, qf[qt][1], c);
        const int sh = kt * 16 + quad * 4;
        float e0 = ((mu >> (sh + 0)) & 1u) ? 0.f : __expf(c[0]);
        float e1 = ((mu >> (sh + 1)) & 1u) ? 0.f : __expf(c[1]);
        float e2 = ((mu >> (sh + 2)) & 1u) ? 0.f : __expf(c[2]);
        float e3 = ((mu >> (sh + 3)) & 1u) ? 0.f : __expf(c[3]);
        lr[qt] += (e0 + e1) + (e2 + e3);
        pun[s][kt][qt][0] = bfpack(e0, e1);
        pun[s][kt][qt][1] = bfpack(e2, e3);
      }
    }
    __builtin_amdgcn_s_setprio(0);
    __syncthreads();                   // all reads of Ks(s) done
    if (s < 7) {
      ((int4*)lk)[0] = n0; ((int4*)lk)[1] = n1;
      ((int4*)lk)[2] = n2; ((int4*)lk)[3] = n3;
    }
    __syncthreads();                   // Ks(s+1) visible
  }

  // ---- L reduction: 2 shfls per qt, then cross-wave via LDS ----
#pragma unroll
  for (int qt = 0; qt < 2; ++qt) {
    float es = lr[qt];
    es += __shfl_xor(es, 16);
    es += __shfl_xor(es, 32);
    if (quad == 0) red[w][qt * 16 + col] = es;
  }
  __syncthreads();
  if (t < 32) {
    float Lx = red[0][t] + red[1][t] + red[2][t] + red[3][t];
    fin[t] = Lx > 0.f ? 1.f / Lx : 0.f;
  }
  __syncthreads();
  float Rq[2];
  Rq[0] = fin[col]; Rq[1] = fin[16 + col];

  const int qh = w & 1, dh = w >> 1;
  v4f ctx[2] = {vz, vz};

  // ---- pass B: normalize from regs -> attn direct write + Pb deposit + PV ----
  float* arow0 = attn + ((size_t)bh * 1024 + q0 + col) * 1024 + w * 32 + quad * 4;
  float* arow1 = arow0 + (size_t)16 * 1024;
  short* pbr0 = Pb + col * 136 + w * 32 + quad * 4;
  short* pbr1 = Pb + (16 + col) * 136 + w * 32 + quad * 4;
#pragma unroll
  for (int s = 0; s < 8; ++s) {
#pragma unroll
    for (int kt = 0; kt < 2; ++kt) {
#pragma unroll
      for (int qt = 0; qt < 2; ++qt) {
        uint32_t u01 = pun[s][kt][qt][0], u23 = pun[s][kt][qt][1];
        float rq = qt ? Rq[1] : Rq[0];
        float f0 = bf2f((uint16_t)u01) * rq, f1 = bf2f((uint16_t)(u01 >> 16)) * rq;
        float f2 = bf2f((uint16_t)u23) * rq, f3 = bf2f((uint16_t)(u23 >> 16)) * rq;
        float4 o = {f0, f1, f2, f3};
        *(float4*)((qt ? arow1 : arow0) + s * 128 + kt * 16) = o;
        short* pb = (qt ? pbr1 : pbr0) + kt * 16;
        *(uint32_t*)pb = bfpack(f0, f1);
        *(uint32_t*)(pb + 2) = bfpack(f2, f3);
      }
    }
    __syncthreads();
    // PV accumulate: pa from Pb; V^T B-fragment DIRECT from global (L2-resident)
    __builtin_amdgcn_s_setprio(1);
#pragma unroll
    for (int kc = 0; kc < 128; kc += 32) {
      v8s pa = *(const v8s*)(Pb + (qh * 16 + col) * 136 + kc + quad * 8);
#pragma unroll
      for (int dt = 0; dt < 2; ++dt) {
        int d = dh * 32 + dt * 16 + col;
        v8s vb = *(const v8s*)(Vt + ((size_t)bh * 64 + d) * 1024 + s * 128 + kc + quad * 8);
        ctx[dt] = mfma16(pa, vb, ctx[dt]);
      }
    }
    __builtin_amdgcn_s_setprio(0);
    __syncthreads();   // Pb consumed before next-iter overwrite
  }
  // write ctx bf16 into [token][h*64+d] layout for the output GEMM
#pragma unroll
  for (int dt = 0; dt < 2; ++dt)
#pragma unroll
    for (int rg = 0; rg < 4; ++rg) {
      int q = q0 + qh * 16 + quad * 4 + rg;
      int d = dh * 32 + dt * 16 + col;
      ctxb[((size_t)(b * 1024 + q)) * 1024 + h * 64 + d] = bf16rn(ctx[dt][rg]);
    }
}

// ---------------- row LayerNorm ----------------
__global__ __launch_bounds__(256) void k_ln(const float* __restrict__ Y,
                                            const float* __restrict__ g,
                                            const float* __restrict__ be,
                                            float* __restrict__ out) {
  __shared__ float sred[4];
  const int row = blockIdx.x, t = threadIdx.x, w = t >> 6, lane = t & 63;
  const float4 v = *(const float4*)(Y + (size_t)row * 1024 + t * 4);
  float sum = v.x + v.y + v.z + v.w;
#pragma unroll
  for (int o = 32; o > 0; o >>= 1) sum += __shfl_down(sum, o);
  if (lane == 0) sred[w] = sum;
  __syncthreads();
  float mu = (sred[0] + sred[1] + sred[2] + sred[3]) * (1.f / 1024.f);
  float dx = v.x - mu, dy = v.y - mu, dz = v.z - mu, dw = v.w - mu;
  float sq = dx * dx + dy * dy + dz * dz + dw * dw;
#pragma unroll
  for (int o = 32; o > 0; o >>= 1) sq += __shfl_down(sq, o);
  __syncthreads();
  if (lane == 0) sred[w] = sq;
  __syncthreads();
  float var = (sred[0] + sred[1] + sred[2] + sred[3]) * (1.f / 1024.f);
  float rs = rsqrtf(var + 1e-6f);
  float4 gg = *(const float4*)(g + t * 4), bb = *(const float4*)(be + t * 4);
  float4 o4;
  o4.x = dx * rs * gg.x + bb.x;
  o4.y = dy * rs * gg.y + bb.y;
  o4.z = dz * rs * gg.z + bb.z;
  o4.w = dw * rs * gg.w + bb.w;
  *(float4*)(out + (size_t)row * 1024 + t * 4) = o4;
}

// ---------------- launch ----------------
extern "C" void kernel_launch(void* const* d_in, const int* in_sizes, int n_in,
                              void* d_out, int out_size, void* d_ws, size_t ws_size,
                              hipStream_t stream) {
  const float* X  = (const float*)d_in[0];
  const int*   Mi = (const int*)d_in[1];
  const float* WQ = (const float*)d_in[2];
  const float* WK = (const float*)d_in[3];
  const float* WV = (const float*)d_in[4];
  const float* WO = (const float*)d_in[5];
  const float* g  = (const float*)d_in[6];
  const float* be = (const float*)d_in[7];

  char* ws = (char*)d_ws;
  short*    Xb  = (short*)(ws + WS_XB);
  short*    Wt  = (short*)(ws + WS_WT);
  short*    WOt = (short*)(ws + WS_WOT);
  uint32_t* Mb  = (uint32_t*)(ws + WS_M8);
  short*    Qb  = (short*)(ws + WS_Q);
  short*    Kb  = (short*)(ws + WS_K);
  short*    Vtb = (short*)(ws + WS_V);   // V^T [bh][64][1024]
  short*    Ctx = Xb;                    // alias: Xb dead after QKV GEMM
  float*    Y   = (float*)(ws + WS_Q);   // alias: Q/K dead after attention

  float* out0 = (float*)d_out;
  float* attn = out0 + (size_t)8 * 1024 * 1024;

  k_prep<<<40960, 256, 0, stream>>>(X, Xb, Mi, Mb);
  k_tw<<<dim3(32, 128), dim3(32, 8), 0, stream>>>(WQ, WK, WV, WO, Wt, WOt);
  k_gemm<0><<<dim3(24, 64), 256, 0, stream>>>(Xb, Wt, Qb, Kb, Vtb, nullptr, nullptr);
  k_attn<<<dim3(32, 128), 256, 0, stream>>>(Qb, Kb, Vtb, Mb, attn, Ctx);
  k_gemm<1><<<dim3(8, 64), 256, 0, stream>>>(Ctx, WOt, nullptr, nullptr, nullptr, X, Y);
  k_ln<<<8192, 256, 0, stream>>>(Y, g, be, out0);
}